// Round 1
// baseline (488.272 us; speedup 1.0000x reference)
//
#include <hip/hip_runtime.h>
#include <hip/hip_bf16.h>
#include <math.h>

#define N_NODES 50000
#define N_EDGES 800000
#define NEG_SLOPE 0.2f

// ---------------- CSR build ----------------
__global__ void count_kernel(const int* __restrict__ ei, int* __restrict__ counts) {
    int e = blockIdx.x * blockDim.x + threadIdx.x;
    if (e < N_EDGES) {
        int dst = ei[N_EDGES + e];
        atomicAdd(&counts[dst], 1);
    }
}

__global__ __launch_bounds__(1024) void scan_kernel(const int* __restrict__ counts,
                                                    int* __restrict__ ptr,
                                                    int* __restrict__ cursor) {
    __shared__ int part[1024];
    int t = threadIdx.x;
    const int CH = (N_NODES + 1023) / 1024; // 49
    int beg = t * CH;
    int end = min(beg + CH, N_NODES);
    int s = 0;
    for (int i = beg; i < end; ++i) s += counts[i];
    part[t] = s;
    __syncthreads();
    // Hillis-Steele inclusive scan over 1024 partials
    for (int d = 1; d < 1024; d <<= 1) {
        int v = (t >= d) ? part[t - d] : 0;
        __syncthreads();
        part[t] += v;
        __syncthreads();
    }
    int run = (t == 0) ? 0 : part[t - 1]; // exclusive prefix of my chunk
    for (int i = beg; i < end; ++i) {
        ptr[i] = run;
        cursor[i] = run;
        run += counts[i];
    }
    if (t == 1023) ptr[N_NODES] = part[1023];
}

__global__ void scatter_kernel(const int* __restrict__ ei, int* __restrict__ cursor,
                               int* __restrict__ csr) {
    int e = blockIdx.x * blockDim.x + threadIdx.x;
    if (e < N_EDGES) {
        int src = ei[e];
        int dst = ei[N_EDGES + e];
        int pos = atomicAdd(&cursor[dst], 1);
        csr[pos] = src;
    }
}

// ---------------- GEMM: H[n][c] = sum_k X[n][k] * W[k][c]   (K=128, C=128) ----
#define GEMM_RB 32
__global__ __launch_bounds__(256) void gemm_kernel(const float* __restrict__ X,
                                                   const float* __restrict__ W,
                                                   float* __restrict__ Hout, int nrows) {
    __shared__ float xt[128][36]; // [k][r], stride 36 keeps float4 alignment, banks ok for bcast reads
    const int tid = threadIdx.x;
    const int r0 = blockIdx.x * GEMM_RB;
    // stage x tile transposed (coalesced global reads)
    #pragma unroll
    for (int i = 0; i < 16; ++i) {
        int idx = tid + 256 * i;         // 0..4095
        int r = idx >> 7, k = idx & 127;
        int gr = r0 + r;
        float v = (gr < nrows) ? X[(size_t)gr * 128 + k] : 0.f;
        xt[k][r] = v;
    }
    __syncthreads();
    const int c = tid & 127;
    const int rb = (tid >> 7) * 16; // 0 or 16; uniform per wave
    float acc[16];
    #pragma unroll
    for (int i = 0; i < 16; ++i) acc[i] = 0.f;
    #pragma unroll 4
    for (int k = 0; k < 128; ++k) {
        float w = W[k * 128 + c];                       // coalesced, L1/L2-hot
        const float4* xp = (const float4*)(&xt[k][rb]); // wave-uniform address -> LDS broadcast
        float4 xa = xp[0], xb = xp[1], xc = xp[2], xd = xp[3];
        acc[0]  = fmaf(xa.x, w, acc[0]);
        acc[1]  = fmaf(xa.y, w, acc[1]);
        acc[2]  = fmaf(xa.z, w, acc[2]);
        acc[3]  = fmaf(xa.w, w, acc[3]);
        acc[4]  = fmaf(xb.x, w, acc[4]);
        acc[5]  = fmaf(xb.y, w, acc[5]);
        acc[6]  = fmaf(xb.z, w, acc[6]);
        acc[7]  = fmaf(xb.w, w, acc[7]);
        acc[8]  = fmaf(xc.x, w, acc[8]);
        acc[9]  = fmaf(xc.y, w, acc[9]);
        acc[10] = fmaf(xc.z, w, acc[10]);
        acc[11] = fmaf(xc.w, w, acc[11]);
        acc[12] = fmaf(xd.x, w, acc[12]);
        acc[13] = fmaf(xd.y, w, acc[13]);
        acc[14] = fmaf(xd.z, w, acc[14]);
        acc[15] = fmaf(xd.w, w, acc[15]);
    }
    #pragma unroll
    for (int i = 0; i < 16; ++i) {
        int gr = r0 + rb + i;
        if (gr < nrows) Hout[(size_t)gr * 128 + c] = acc[i];
    }
}

// ---------------- per-node attention logits ----------------
// H==2: channels 0..63 = head0, 64..127 = head1 (C=64)
// H==1: single head, C=128
template <int H>
__global__ __launch_bounds__(256) void alpha_kernel(const float* __restrict__ Hm,
                                                    const float* __restrict__ a_src,
                                                    const float* __restrict__ a_dst,
                                                    float* __restrict__ als,
                                                    float* __restrict__ ald) {
    int wid = ((blockIdx.x * blockDim.x + threadIdx.x) >> 6);
    int lane = threadIdx.x & 63;
    if (wid >= N_NODES) return;
    float v0 = Hm[(size_t)wid * 128 + lane];
    float v1 = Hm[(size_t)wid * 128 + 64 + lane];
    if (H == 2) {
        float s0 = v0 * a_src[lane];
        float s1 = v1 * a_src[64 + lane];
        float d0 = v0 * a_dst[lane];
        float d1 = v1 * a_dst[64 + lane];
        #pragma unroll
        for (int off = 32; off; off >>= 1) {
            s0 += __shfl_down(s0, off);
            s1 += __shfl_down(s1, off);
            d0 += __shfl_down(d0, off);
            d1 += __shfl_down(d1, off);
        }
        if (lane == 0) {
            als[wid * 2] = s0; als[wid * 2 + 1] = s1;
            ald[wid * 2] = d0; ald[wid * 2 + 1] = d1;
        }
    } else {
        float s = v0 * a_src[lane] + v1 * a_src[64 + lane];
        float d = v0 * a_dst[lane] + v1 * a_dst[64 + lane];
        #pragma unroll
        for (int off = 32; off; off >>= 1) {
            s += __shfl_down(s, off);
            d += __shfl_down(d, off);
        }
        if (lane == 0) { als[wid] = s; ald[wid] = d; }
    }
}

// ---------------- fused edge-softmax + aggregation (one wave per dst node) ----
template <int H, int DO_ELU>
__global__ __launch_bounds__(256) void aggregate_kernel(const float* __restrict__ Hm,
                                                        const float* __restrict__ als,
                                                        const float* __restrict__ aldv,
                                                        const int* __restrict__ ptr,
                                                        const int* __restrict__ csr,
                                                        const float* __restrict__ bias,
                                                        float* __restrict__ out) {
    int wid = blockIdx.x * (blockDim.x >> 6) + (threadIdx.x >> 6);
    int lane = threadIdx.x & 63;
    if (wid >= N_NODES) return;
    const int d = wid;
    const int head = (H == 2) ? (lane >> 5) : 0;
    const float ald = aldv[d * H + head];

    float m, l, a0, a1;
    { // self-loop (reference appends one per node)
        float e = als[d * H + head] + ald;
        e = e > 0.f ? e : NEG_SLOPE * e;
        m = e; l = 1.f;
        float2 hv = ((const float2*)(Hm + (size_t)d * 128))[lane];
        a0 = hv.x; a1 = hv.y;
    }
    int beg = ptr[d], end = ptr[d + 1];
    for (int k = beg; k < end; ++k) {
        int src = csr[k];
        float e = als[src * H + head] + ald;
        e = e > 0.f ? e : NEG_SLOPE * e;
        float mn = fmaxf(m, e);
        float sc = __expf(m - mn);
        float p = __expf(e - mn);
        float2 hv = ((const float2*)(Hm + (size_t)src * 128))[lane];
        l = fmaf(l, sc, p);
        a0 = fmaf(a0, sc, p * hv.x);
        a1 = fmaf(a1, sc, p * hv.y);
        m = mn;
    }
    float inv = 1.f / (l + 1e-16f);
    float o0 = a0 * inv + bias[2 * lane];
    float o1 = a1 * inv + bias[2 * lane + 1];
    if (DO_ELU) {
        o0 = o0 > 0.f ? o0 : expm1f(o0);
        o1 = o1 > 0.f ? o1 : expm1f(o1);
    }
    ((float2*)(out + (size_t)d * 128))[lane] = make_float2(o0, o1);
}

// ---------------- launch ----------------
extern "C" void kernel_launch(void* const* d_in, const int* in_sizes, int n_in,
                              void* d_out, int out_size, void* d_ws, size_t ws_size,
                              hipStream_t stream) {
    const float* x      = (const float*)d_in[0];
    const int*   ei     = (const int*)d_in[1];
    const float* W1     = (const float*)d_in[2];
    const float* a_src1 = (const float*)d_in[3];
    const float* a_dst1 = (const float*)d_in[4];
    const float* b1     = (const float*)d_in[5];
    const float* W2     = (const float*)d_in[6];
    const float* a_src2 = (const float*)d_in[7];
    const float* a_dst2 = (const float*)d_in[8];
    const float* b2     = (const float*)d_in[9];
    float* out = (float*)d_out;

    // workspace layout (256B aligned)
    char* ws = (char*)d_ws;
    size_t off = 0;
    auto alloc = [&](size_t bytes) { void* p = ws + off; off += (bytes + 255) & ~(size_t)255; return p; };
    int*   ptr    = (int*)alloc((N_NODES + 1) * sizeof(int));
    int*   cursor = (int*)alloc(N_NODES * sizeof(int));
    int*   counts = (int*)alloc(N_NODES * sizeof(int));
    int*   csr    = (int*)alloc(N_EDGES * sizeof(int));
    float* h      = (float*)alloc((size_t)N_NODES * 128 * sizeof(float)); // h1 then h2
    float* x2     = (float*)alloc((size_t)N_NODES * 128 * sizeof(float));
    float* als    = (float*)alloc(N_NODES * 2 * sizeof(float));
    float* ald    = (float*)alloc(N_NODES * 2 * sizeof(float));

    // ---- CSR build (same graph both layers) ----
    hipMemsetAsync(counts, 0, N_NODES * sizeof(int), stream);
    int eblocks = (N_EDGES + 255) / 256;
    count_kernel<<<eblocks, 256, 0, stream>>>(ei, counts);
    scan_kernel<<<1, 1024, 0, stream>>>(counts, ptr, cursor);
    scatter_kernel<<<eblocks, 256, 0, stream>>>(ei, cursor, csr);

    int gblocks = (N_NODES + GEMM_RB - 1) / GEMM_RB;
    int wblocks = (N_NODES + 3) / 4; // 4 waves per 256-thread block

    // ---- layer 1 ----
    gemm_kernel<<<gblocks, 256, 0, stream>>>(x, W1, h, N_NODES);
    alpha_kernel<2><<<wblocks, 256, 0, stream>>>(h, a_src1, a_dst1, als, ald);
    aggregate_kernel<2, 1><<<wblocks, 256, 0, stream>>>(h, als, ald, ptr, csr, b1, x2);

    // ---- layer 2 ----
    gemm_kernel<<<gblocks, 256, 0, stream>>>(x2, W2, h, N_NODES);
    alpha_kernel<1><<<wblocks, 256, 0, stream>>>(h, a_src2, a_dst2, als, ald);
    aggregate_kernel<1, 0><<<wblocks, 256, 0, stream>>>(h, als, ald, ptr, csr, b2, out);
}

// Round 2
// 388.088 us; speedup vs baseline: 1.2581x; 1.2581x over previous
//
#include <hip/hip_runtime.h>
#include <hip/hip_bf16.h>
#include <math.h>

#define N_NODES 50000
#define N_EDGES 800000
#define NEG_SLOPE 0.2f
#define SCAN_NBLK ((N_NODES + 1023) / 1024)   // 49

// ---------------- CSR build ----------------
__global__ void count_kernel(const int* __restrict__ ei, int* __restrict__ counts) {
    int e = blockIdx.x * blockDim.x + threadIdx.x;
    if (e < N_EDGES) {
        int dst = ei[N_EDGES + e];
        atomicAdd(&counts[dst], 1);
    }
}

// pass 1: per-block (1024 elems) sums
__global__ __launch_bounds__(256) void blocksum_kernel(const int* __restrict__ counts,
                                                       int* __restrict__ partials) {
    int base = blockIdx.x * 1024 + threadIdx.x * 4;
    int s = 0;
    if (base + 3 < N_NODES) {
        int4 v = *(const int4*)(counts + base);
        s = v.x + v.y + v.z + v.w;
    } else {
        #pragma unroll
        for (int i = 0; i < 4; ++i) if (base + i < N_NODES) s += counts[base + i];
    }
    #pragma unroll
    for (int off = 32; off; off >>= 1) s += __shfl_down(s, off);
    __shared__ int wsum[4];
    int lane = threadIdx.x & 63, w = threadIdx.x >> 6;
    if (lane == 0) wsum[w] = s;
    __syncthreads();
    if (threadIdx.x == 0) partials[blockIdx.x] = wsum[0] + wsum[1] + wsum[2] + wsum[3];
}

// pass 2: single-wave inclusive scan of the 49 partials; also ptr[N] = E
__global__ void scanpartials_kernel(int* __restrict__ partials, int* __restrict__ ptr) {
    int t = threadIdx.x;                    // 64 threads
    int v = (t < SCAN_NBLK) ? partials[t] : 0;
    #pragma unroll
    for (int off = 1; off < 64; off <<= 1) {
        int u = __shfl_up(v, off);
        if (t >= off) v += u;
    }
    if (t < SCAN_NBLK) partials[t] = v;     // inclusive
    if (t == 0) ptr[N_NODES] = N_EDGES;     // total is constant
}

// pass 3: in-block exclusive scan + block offset -> ptr, cursor
__global__ __launch_bounds__(256) void downsweep_kernel(const int* __restrict__ counts,
                                                        const int* __restrict__ partials,
                                                        int* __restrict__ ptr,
                                                        int* __restrict__ cursor) {
    int b = blockIdx.x;
    int t = threadIdx.x;
    int idx = b * 1024 + t * 4;
    int v[4] = {0, 0, 0, 0};
    if (idx + 3 < N_NODES) {
        int4 q = *(const int4*)(counts + idx);
        v[0] = q.x; v[1] = q.y; v[2] = q.z; v[3] = q.w;
    } else {
        #pragma unroll
        for (int i = 0; i < 4; ++i) if (idx + i < N_NODES) v[i] = counts[idx + i];
    }
    int s = v[0] + v[1] + v[2] + v[3];
    int lane = t & 63, w = t >> 6;
    int inc = s;
    #pragma unroll
    for (int off = 1; off < 64; off <<= 1) {
        int u = __shfl_up(inc, off);
        if (lane >= off) inc += u;
    }
    __shared__ int wsum[4];
    if (lane == 63) wsum[w] = inc;
    __syncthreads();
    int wpre = 0;
    #pragma unroll
    for (int i = 0; i < 4; ++i) if (i < w) wpre += wsum[i];
    int excl = wpre + inc - s;              // exclusive prefix of this thread in block
    int run = ((b == 0) ? 0 : partials[b - 1]) + excl;
    #pragma unroll
    for (int i = 0; i < 4; ++i) {
        if (idx + i < N_NODES) {
            ptr[idx + i] = run;
            cursor[idx + i] = run;
            run += v[i];
        }
    }
}

__global__ void scatter_kernel(const int* __restrict__ ei, int* __restrict__ cursor,
                               int* __restrict__ csr) {
    int e = blockIdx.x * blockDim.x + threadIdx.x;
    if (e < N_EDGES) {
        int src = ei[e];
        int dst = ei[N_EDGES + e];
        int pos = atomicAdd(&cursor[dst], 1);
        csr[pos] = src;
    }
}

// ---------------- GEMM: H[n][c] = sum_k X[n][k] * W[k][c]   (K=128, C=128) ----
#define GEMM_RB 32
__global__ __launch_bounds__(256) void gemm_kernel(const float* __restrict__ X,
                                                   const float* __restrict__ W,
                                                   float* __restrict__ Hout, int nrows) {
    __shared__ float xt[128][36];
    const int tid = threadIdx.x;
    const int r0 = blockIdx.x * GEMM_RB;
    #pragma unroll
    for (int i = 0; i < 16; ++i) {
        int idx = tid + 256 * i;
        int r = idx >> 7, k = idx & 127;
        int gr = r0 + r;
        float v = (gr < nrows) ? X[(size_t)gr * 128 + k] : 0.f;
        xt[k][r] = v;
    }
    __syncthreads();
    const int c = tid & 127;
    const int rb = (tid >> 7) * 16;
    float acc[16];
    #pragma unroll
    for (int i = 0; i < 16; ++i) acc[i] = 0.f;
    #pragma unroll 4
    for (int k = 0; k < 128; ++k) {
        float w = W[k * 128 + c];
        const float4* xp = (const float4*)(&xt[k][rb]);
        float4 xa = xp[0], xb = xp[1], xc = xp[2], xd = xp[3];
        acc[0]  = fmaf(xa.x, w, acc[0]);
        acc[1]  = fmaf(xa.y, w, acc[1]);
        acc[2]  = fmaf(xa.z, w, acc[2]);
        acc[3]  = fmaf(xa.w, w, acc[3]);
        acc[4]  = fmaf(xb.x, w, acc[4]);
        acc[5]  = fmaf(xb.y, w, acc[5]);
        acc[6]  = fmaf(xb.z, w, acc[6]);
        acc[7]  = fmaf(xb.w, w, acc[7]);
        acc[8]  = fmaf(xc.x, w, acc[8]);
        acc[9]  = fmaf(xc.y, w, acc[9]);
        acc[10] = fmaf(xc.z, w, acc[10]);
        acc[11] = fmaf(xc.w, w, acc[11]);
        acc[12] = fmaf(xd.x, w, acc[12]);
        acc[13] = fmaf(xd.y, w, acc[13]);
        acc[14] = fmaf(xd.z, w, acc[14]);
        acc[15] = fmaf(xd.w, w, acc[15]);
    }
    #pragma unroll
    for (int i = 0; i < 16; ++i) {
        int gr = r0 + rb + i;
        if (gr < nrows) Hout[(size_t)gr * 128 + c] = acc[i];
    }
}

// ---------------- per-node attention logits ----------------
template <int H>
__global__ __launch_bounds__(256) void alpha_kernel(const float* __restrict__ Hm,
                                                    const float* __restrict__ a_src,
                                                    const float* __restrict__ a_dst,
                                                    float* __restrict__ als,
                                                    float* __restrict__ ald) {
    int wid = ((blockIdx.x * blockDim.x + threadIdx.x) >> 6);
    int lane = threadIdx.x & 63;
    if (wid >= N_NODES) return;
    float v0 = Hm[(size_t)wid * 128 + lane];
    float v1 = Hm[(size_t)wid * 128 + 64 + lane];
    if (H == 2) {
        float s0 = v0 * a_src[lane];
        float s1 = v1 * a_src[64 + lane];
        float d0 = v0 * a_dst[lane];
        float d1 = v1 * a_dst[64 + lane];
        #pragma unroll
        for (int off = 32; off; off >>= 1) {
            s0 += __shfl_down(s0, off);
            s1 += __shfl_down(s1, off);
            d0 += __shfl_down(d0, off);
            d1 += __shfl_down(d1, off);
        }
        if (lane == 0) {
            als[wid * 2] = s0; als[wid * 2 + 1] = s1;
            ald[wid * 2] = d0; ald[wid * 2 + 1] = d1;
        }
    } else {
        float s = v0 * a_src[lane] + v1 * a_src[64 + lane];
        float d = v0 * a_dst[lane] + v1 * a_dst[64 + lane];
        #pragma unroll
        for (int off = 32; off; off >>= 1) {
            s += __shfl_down(s, off);
            d += __shfl_down(d, off);
        }
        if (lane == 0) { als[wid] = s; ald[wid] = d; }
    }
}

// ---------------- fused edge-softmax + aggregation (one wave per dst node) ----
template <int H, int DO_ELU>
__global__ __launch_bounds__(256) void aggregate_kernel(const float* __restrict__ Hm,
                                                        const float* __restrict__ als,
                                                        const float* __restrict__ aldv,
                                                        const int* __restrict__ ptr,
                                                        const int* __restrict__ csr,
                                                        const float* __restrict__ bias,
                                                        float* __restrict__ out) {
    int wid = blockIdx.x * (blockDim.x >> 6) + (threadIdx.x >> 6);
    int lane = threadIdx.x & 63;
    if (wid >= N_NODES) return;
    const int d = wid;
    const int head = (H == 2) ? (lane >> 5) : 0;
    const float ald = aldv[d * H + head];

    float m, l, a0, a1;
    {
        float e = als[d * H + head] + ald;
        e = e > 0.f ? e : NEG_SLOPE * e;
        m = e; l = 1.f;
        float2 hv = ((const float2*)(Hm + (size_t)d * 128))[lane];
        a0 = hv.x; a1 = hv.y;
    }
    int beg = ptr[d], end = ptr[d + 1];
    for (int k = beg; k < end; ++k) {
        int src = csr[k];
        float e = als[src * H + head] + ald;
        e = e > 0.f ? e : NEG_SLOPE * e;
        float mn = fmaxf(m, e);
        float sc = __expf(m - mn);
        float p = __expf(e - mn);
        float2 hv = ((const float2*)(Hm + (size_t)src * 128))[lane];
        l = fmaf(l, sc, p);
        a0 = fmaf(a0, sc, p * hv.x);
        a1 = fmaf(a1, sc, p * hv.y);
        m = mn;
    }
    float inv = 1.f / (l + 1e-16f);
    float o0 = a0 * inv + bias[2 * lane];
    float o1 = a1 * inv + bias[2 * lane + 1];
    if (DO_ELU) {
        o0 = o0 > 0.f ? o0 : expm1f(o0);
        o1 = o1 > 0.f ? o1 : expm1f(o1);
    }
    ((float2*)(out + (size_t)d * 128))[lane] = make_float2(o0, o1);
}

// ---------------- launch ----------------
extern "C" void kernel_launch(void* const* d_in, const int* in_sizes, int n_in,
                              void* d_out, int out_size, void* d_ws, size_t ws_size,
                              hipStream_t stream) {
    const float* x      = (const float*)d_in[0];
    const int*   ei     = (const int*)d_in[1];
    const float* W1     = (const float*)d_in[2];
    const float* a_src1 = (const float*)d_in[3];
    const float* a_dst1 = (const float*)d_in[4];
    const float* b1     = (const float*)d_in[5];
    const float* W2     = (const float*)d_in[6];
    const float* a_src2 = (const float*)d_in[7];
    const float* a_dst2 = (const float*)d_in[8];
    const float* b2     = (const float*)d_in[9];
    float* out = (float*)d_out;

    char* ws = (char*)d_ws;
    size_t off = 0;
    auto alloc = [&](size_t bytes) { void* p = ws + off; off += (bytes + 255) & ~(size_t)255; return p; };
    int*   ptr      = (int*)alloc((N_NODES + 1) * sizeof(int));
    int*   cursor   = (int*)alloc(N_NODES * sizeof(int));
    int*   counts   = (int*)alloc(N_NODES * sizeof(int));
    int*   partials = (int*)alloc(SCAN_NBLK * sizeof(int));
    int*   csr      = (int*)alloc(N_EDGES * sizeof(int));
    float* h        = (float*)alloc((size_t)N_NODES * 128 * sizeof(float));
    float* x2       = (float*)alloc((size_t)N_NODES * 128 * sizeof(float));
    float* als      = (float*)alloc(N_NODES * 2 * sizeof(float));
    float* ald      = (float*)alloc(N_NODES * 2 * sizeof(float));

    // ---- CSR build (same graph both layers) ----
    hipMemsetAsync(counts, 0, N_NODES * sizeof(int), stream);
    int eblocks = (N_EDGES + 255) / 256;
    count_kernel<<<eblocks, 256, 0, stream>>>(ei, counts);
    blocksum_kernel<<<SCAN_NBLK, 256, 0, stream>>>(counts, partials);
    scanpartials_kernel<<<1, 64, 0, stream>>>(partials, ptr);
    downsweep_kernel<<<SCAN_NBLK, 256, 0, stream>>>(counts, partials, ptr, cursor);
    scatter_kernel<<<eblocks, 256, 0, stream>>>(ei, cursor, csr);

    int gblocks = (N_NODES + GEMM_RB - 1) / GEMM_RB;
    int wblocks = (N_NODES + 3) / 4;

    // ---- layer 1 ----
    gemm_kernel<<<gblocks, 256, 0, stream>>>(x, W1, h, N_NODES);
    alpha_kernel<2><<<wblocks, 256, 0, stream>>>(h, a_src1, a_dst1, als, ald);
    aggregate_kernel<2, 1><<<wblocks, 256, 0, stream>>>(h, als, ald, ptr, csr, b1, x2);

    // ---- layer 2 ----
    gemm_kernel<<<gblocks, 256, 0, stream>>>(x2, W2, h, N_NODES);
    alpha_kernel<1><<<wblocks, 256, 0, stream>>>(h, a_src2, a_dst2, als, ald);
    aggregate_kernel<1, 0><<<wblocks, 256, 0, stream>>>(h, als, ald, ptr, csr, b2, out);
}

// Round 3
// 320.190 us; speedup vs baseline: 1.5249x; 1.2121x over previous
//
#include <hip/hip_runtime.h>
#include <hip/hip_bf16.h>
#include <math.h>

#define N_NODES 50000
#define N_EDGES 800000
#define NEG_SLOPE 0.2f
#define SCAN_NBLK ((N_NODES + 1023) / 1024)   // 49

// ---------------- CSR build ----------------
__global__ void count_kernel(const int* __restrict__ ei, int* __restrict__ counts) {
    int e = blockIdx.x * blockDim.x + threadIdx.x;
    if (e < N_EDGES) {
        int dst = ei[N_EDGES + e];
        atomicAdd(&counts[dst], 1);
    }
}

__global__ __launch_bounds__(256) void blocksum_kernel(const int* __restrict__ counts,
                                                       int* __restrict__ partials) {
    int base = blockIdx.x * 1024 + threadIdx.x * 4;
    int s = 0;
    if (base + 3 < N_NODES) {
        int4 v = *(const int4*)(counts + base);
        s = v.x + v.y + v.z + v.w;
    } else {
        #pragma unroll
        for (int i = 0; i < 4; ++i) if (base + i < N_NODES) s += counts[base + i];
    }
    #pragma unroll
    for (int off = 32; off; off >>= 1) s += __shfl_down(s, off);
    __shared__ int wsum[4];
    int lane = threadIdx.x & 63, w = threadIdx.x >> 6;
    if (lane == 0) wsum[w] = s;
    __syncthreads();
    if (threadIdx.x == 0) partials[blockIdx.x] = wsum[0] + wsum[1] + wsum[2] + wsum[3];
}

__global__ void scanpartials_kernel(int* __restrict__ partials, int* __restrict__ ptr) {
    int t = threadIdx.x;
    int v = (t < SCAN_NBLK) ? partials[t] : 0;
    #pragma unroll
    for (int off = 1; off < 64; off <<= 1) {
        int u = __shfl_up(v, off);
        if (t >= off) v += u;
    }
    if (t < SCAN_NBLK) partials[t] = v;
    if (t == 0) ptr[N_NODES] = N_EDGES;
}

__global__ __launch_bounds__(256) void downsweep_kernel(const int* __restrict__ counts,
                                                        const int* __restrict__ partials,
                                                        int* __restrict__ ptr,
                                                        int* __restrict__ cursor) {
    int b = blockIdx.x;
    int t = threadIdx.x;
    int idx = b * 1024 + t * 4;
    int v[4] = {0, 0, 0, 0};
    if (idx + 3 < N_NODES) {
        int4 q = *(const int4*)(counts + idx);
        v[0] = q.x; v[1] = q.y; v[2] = q.z; v[3] = q.w;
    } else {
        #pragma unroll
        for (int i = 0; i < 4; ++i) if (idx + i < N_NODES) v[i] = counts[idx + i];
    }
    int s = v[0] + v[1] + v[2] + v[3];
    int lane = t & 63, w = t >> 6;
    int inc = s;
    #pragma unroll
    for (int off = 1; off < 64; off <<= 1) {
        int u = __shfl_up(inc, off);
        if (lane >= off) inc += u;
    }
    __shared__ int wsum[4];
    if (lane == 63) wsum[w] = inc;
    __syncthreads();
    int wpre = 0;
    #pragma unroll
    for (int i = 0; i < 4; ++i) if (i < w) wpre += wsum[i];
    int excl = wpre + inc - s;
    int run = ((b == 0) ? 0 : partials[b - 1]) + excl;
    #pragma unroll
    for (int i = 0; i < 4; ++i) {
        if (idx + i < N_NODES) {
            ptr[idx + i] = run;
            cursor[idx + i] = run;
            run += v[i];
        }
    }
}

__global__ void scatter_kernel(const int* __restrict__ ei, int* __restrict__ cursor,
                               int* __restrict__ csr) {
    int e = blockIdx.x * blockDim.x + threadIdx.x;
    if (e < N_EDGES) {
        int src = ei[e];
        int dst = ei[N_EDGES + e];
        int pos = atomicAdd(&cursor[dst], 1);
        csr[pos] = src;
    }
}

// ---------------- GEMM: H[n][c] = sum_k X[n][k] * W[k][c]   (K=128, C=128) ----
#define GEMM_RB 32
__global__ __launch_bounds__(256) void gemm_kernel(const float* __restrict__ X,
                                                   const float* __restrict__ W,
                                                   float* __restrict__ Hout, int nrows) {
    __shared__ float xt[128][36];
    const int tid = threadIdx.x;
    const int r0 = blockIdx.x * GEMM_RB;
    #pragma unroll
    for (int i = 0; i < 16; ++i) {
        int idx = tid + 256 * i;
        int r = idx >> 7, k = idx & 127;
        int gr = r0 + r;
        float v = (gr < nrows) ? X[(size_t)gr * 128 + k] : 0.f;
        xt[k][r] = v;
    }
    __syncthreads();
    const int c = tid & 127;
    const int rb = (tid >> 7) * 16;
    float acc[16];
    #pragma unroll
    for (int i = 0; i < 16; ++i) acc[i] = 0.f;
    #pragma unroll 4
    for (int k = 0; k < 128; ++k) {
        float w = W[k * 128 + c];
        const float4* xp = (const float4*)(&xt[k][rb]);
        float4 xa = xp[0], xb = xp[1], xc = xp[2], xd = xp[3];
        acc[0]  = fmaf(xa.x, w, acc[0]);
        acc[1]  = fmaf(xa.y, w, acc[1]);
        acc[2]  = fmaf(xa.z, w, acc[2]);
        acc[3]  = fmaf(xa.w, w, acc[3]);
        acc[4]  = fmaf(xb.x, w, acc[4]);
        acc[5]  = fmaf(xb.y, w, acc[5]);
        acc[6]  = fmaf(xb.z, w, acc[6]);
        acc[7]  = fmaf(xb.w, w, acc[7]);
        acc[8]  = fmaf(xc.x, w, acc[8]);
        acc[9]  = fmaf(xc.y, w, acc[9]);
        acc[10] = fmaf(xc.z, w, acc[10]);
        acc[11] = fmaf(xc.w, w, acc[11]);
        acc[12] = fmaf(xd.x, w, acc[12]);
        acc[13] = fmaf(xd.y, w, acc[13]);
        acc[14] = fmaf(xd.z, w, acc[14]);
        acc[15] = fmaf(xd.w, w, acc[15]);
    }
    #pragma unroll
    for (int i = 0; i < 16; ++i) {
        int gr = r0 + rb + i;
        if (gr < nrows) Hout[(size_t)gr * 128 + c] = acc[i];
    }
}

// ---------------- per-node attention logits ----------------
template <int H>
__global__ __launch_bounds__(256) void alpha_kernel(const float* __restrict__ Hm,
                                                    const float* __restrict__ a_src,
                                                    const float* __restrict__ a_dst,
                                                    float* __restrict__ als,
                                                    float* __restrict__ ald) {
    int wid = ((blockIdx.x * blockDim.x + threadIdx.x) >> 6);
    int lane = threadIdx.x & 63;
    if (wid >= N_NODES) return;
    float v0 = Hm[(size_t)wid * 128 + lane];
    float v1 = Hm[(size_t)wid * 128 + 64 + lane];
    if (H == 2) {
        float s0 = v0 * a_src[lane];
        float s1 = v1 * a_src[64 + lane];
        float d0 = v0 * a_dst[lane];
        float d1 = v1 * a_dst[64 + lane];
        #pragma unroll
        for (int off = 32; off; off >>= 1) {
            s0 += __shfl_down(s0, off);
            s1 += __shfl_down(s1, off);
            d0 += __shfl_down(d0, off);
            d1 += __shfl_down(d1, off);
        }
        if (lane == 0) {
            als[wid * 2] = s0; als[wid * 2 + 1] = s1;
            ald[wid * 2] = d0; ald[wid * 2 + 1] = d1;
        }
    } else {
        float s = v0 * a_src[lane] + v1 * a_src[64 + lane];
        float d = v0 * a_dst[lane] + v1 * a_dst[64 + lane];
        #pragma unroll
        for (int off = 32; off; off >>= 1) {
            s += __shfl_down(s, off);
            d += __shfl_down(d, off);
        }
        if (lane == 0) { als[wid] = s; ald[wid] = d; }
    }
}

// ---------------- fused edge-softmax + aggregation (one wave per dst node) ----
// 4 independent online-softmax states -> 4 gather chains in flight per wave.
template <int H, int DO_ELU>
__global__ __launch_bounds__(256) void aggregate_kernel(const float* __restrict__ Hm,
                                                        const float* __restrict__ als,
                                                        const float* __restrict__ aldv,
                                                        const int* __restrict__ ptr,
                                                        const int* __restrict__ csr,
                                                        const float* __restrict__ bias,
                                                        float* __restrict__ out) {
    int wid = blockIdx.x * (blockDim.x >> 6) + (threadIdx.x >> 6);
    int lane = threadIdx.x & 63;
    if (wid >= N_NODES) return;
    const int d = wid;
    const int head = (H == 2) ? (lane >> 5) : 0;
    const float ald = aldv[d * H + head];

    float m0, m1, m2, m3, l0, l1, l2, l3;
    float a0x, a0y, a1x, a1y, a2x, a2y, a3x, a3y;
    { // state 0 init = self-loop
        float e = als[d * H + head] + ald;
        e = e > 0.f ? e : NEG_SLOPE * e;
        m0 = e; l0 = 1.f;
        float2 hv = ((const float2*)(Hm + (size_t)d * 128))[lane];
        a0x = hv.x; a0y = hv.y;
    }
    m1 = m2 = m3 = -INFINITY;
    l1 = l2 = l3 = 0.f;
    a1x = a1y = a2x = a2y = a3x = a3y = 0.f;

#define UPDATE(S, SRC) do {                                                   \
        int _s = (SRC);                                                       \
        float _e = als[_s * H + head] + ald;                                  \
        _e = _e > 0.f ? _e : NEG_SLOPE * _e;                                  \
        float2 _hv = ((const float2*)(Hm + (size_t)_s * 128))[lane];          \
        float _mn = fmaxf(m##S, _e);                                          \
        float _sc = __expf(m##S - _mn);                                       \
        float _p  = __expf(_e - _mn);                                         \
        l##S  = fmaf(l##S, _sc, _p);                                          \
        a##S##x = fmaf(a##S##x, _sc, _p * _hv.x);                             \
        a##S##y = fmaf(a##S##y, _sc, _p * _hv.y);                             \
        m##S = _mn;                                                           \
    } while (0)

    int beg = ptr[d], end = ptr[d + 1];
    int k = beg;
    for (; k + 3 < end; k += 4) {
        int s0 = csr[k], s1 = csr[k + 1], s2 = csr[k + 2], s3 = csr[k + 3];
        UPDATE(0, s0);
        UPDATE(1, s1);
        UPDATE(2, s2);
        UPDATE(3, s3);
    }
    if (k < end) { UPDATE(0, csr[k]); ++k; }
    if (k < end) { UPDATE(1, csr[k]); ++k; }
    if (k < end) { UPDATE(2, csr[k]); ++k; }
#undef UPDATE

    // merge the 4 states (exp(-inf - M) == 0 handles empty states)
    float M = fmaxf(fmaxf(m0, m1), fmaxf(m2, m3));
    float w0 = __expf(m0 - M), w1 = __expf(m1 - M);
    float w2 = __expf(m2 - M), w3 = __expf(m3 - M);
    float L  = l0 * w0 + l1 * w1 + l2 * w2 + l3 * w3;
    float ax = a0x * w0 + a1x * w1 + a2x * w2 + a3x * w3;
    float ay = a0y * w0 + a1y * w1 + a2y * w2 + a3y * w3;

    float inv = 1.f / (L + 1e-16f);
    float o0 = ax * inv + bias[2 * lane];
    float o1 = ay * inv + bias[2 * lane + 1];
    if (DO_ELU) {
        o0 = o0 > 0.f ? o0 : expm1f(o0);
        o1 = o1 > 0.f ? o1 : expm1f(o1);
    }
    ((float2*)(out + (size_t)d * 128))[lane] = make_float2(o0, o1);
}

// ---------------- launch ----------------
extern "C" void kernel_launch(void* const* d_in, const int* in_sizes, int n_in,
                              void* d_out, int out_size, void* d_ws, size_t ws_size,
                              hipStream_t stream) {
    const float* x      = (const float*)d_in[0];
    const int*   ei     = (const int*)d_in[1];
    const float* W1     = (const float*)d_in[2];
    const float* a_src1 = (const float*)d_in[3];
    const float* a_dst1 = (const float*)d_in[4];
    const float* b1     = (const float*)d_in[5];
    const float* W2     = (const float*)d_in[6];
    const float* a_src2 = (const float*)d_in[7];
    const float* a_dst2 = (const float*)d_in[8];
    const float* b2     = (const float*)d_in[9];
    float* out = (float*)d_out;

    char* ws = (char*)d_ws;
    size_t off = 0;
    auto alloc = [&](size_t bytes) { void* p = ws + off; off += (bytes + 255) & ~(size_t)255; return p; };
    int*   ptr      = (int*)alloc((N_NODES + 1) * sizeof(int));
    int*   cursor   = (int*)alloc(N_NODES * sizeof(int));
    int*   counts   = (int*)alloc(N_NODES * sizeof(int));
    int*   partials = (int*)alloc(SCAN_NBLK * sizeof(int));
    int*   csr      = (int*)alloc(N_EDGES * sizeof(int));
    float* h        = (float*)alloc((size_t)N_NODES * 128 * sizeof(float));
    float* x2       = (float*)alloc((size_t)N_NODES * 128 * sizeof(float));
    float* als      = (float*)alloc(N_NODES * 2 * sizeof(float));
    float* ald      = (float*)alloc(N_NODES * 2 * sizeof(float));

    // ---- CSR build (same graph both layers) ----
    hipMemsetAsync(counts, 0, N_NODES * sizeof(int), stream);
    int eblocks = (N_EDGES + 255) / 256;
    count_kernel<<<eblocks, 256, 0, stream>>>(ei, counts);
    blocksum_kernel<<<SCAN_NBLK, 256, 0, stream>>>(counts, partials);
    scanpartials_kernel<<<1, 64, 0, stream>>>(partials, ptr);
    downsweep_kernel<<<SCAN_NBLK, 256, 0, stream>>>(counts, partials, ptr, cursor);
    scatter_kernel<<<eblocks, 256, 0, stream>>>(ei, cursor, csr);

    int gblocks = (N_NODES + GEMM_RB - 1) / GEMM_RB;
    int wblocks = (N_NODES + 3) / 4;

    // ---- layer 1 ----
    gemm_kernel<<<gblocks, 256, 0, stream>>>(x, W1, h, N_NODES);
    alpha_kernel<2><<<wblocks, 256, 0, stream>>>(h, a_src1, a_dst1, als, ald);
    aggregate_kernel<2, 1><<<wblocks, 256, 0, stream>>>(h, als, ald, ptr, csr, b1, x2);

    // ---- layer 2 ----
    gemm_kernel<<<gblocks, 256, 0, stream>>>(x2, W2, h, N_NODES);
    alpha_kernel<1><<<wblocks, 256, 0, stream>>>(h, a_src2, a_dst2, als, ald);
    aggregate_kernel<1, 0><<<wblocks, 256, 0, stream>>>(h, als, ald, ptr, csr, b2, out);
}

// Round 4
// 281.662 us; speedup vs baseline: 1.7335x; 1.1368x over previous
//
#include <hip/hip_runtime.h>
#include <hip/hip_bf16.h>
#include <math.h>

#define N_NODES 50000
#define N_EDGES 800000
#define NEG_SLOPE 0.2f
#define SCAN_NBLK ((N_NODES + 1023) / 1024)   // 49

// ---------------- CSR build ----------------
__global__ void count_kernel(const int* __restrict__ ei, int* __restrict__ counts) {
    int e = blockIdx.x * blockDim.x + threadIdx.x;
    if (e < N_EDGES) {
        int dst = ei[N_EDGES + e];
        atomicAdd(&counts[dst], 1);
    }
}

__global__ __launch_bounds__(256) void blocksum_kernel(const int* __restrict__ counts,
                                                       int* __restrict__ partials) {
    int base = blockIdx.x * 1024 + threadIdx.x * 4;
    int s = 0;
    if (base + 3 < N_NODES) {
        int4 v = *(const int4*)(counts + base);
        s = v.x + v.y + v.z + v.w;
    } else {
        #pragma unroll
        for (int i = 0; i < 4; ++i) if (base + i < N_NODES) s += counts[base + i];
    }
    #pragma unroll
    for (int off = 32; off; off >>= 1) s += __shfl_down(s, off);
    __shared__ int wsum[4];
    int lane = threadIdx.x & 63, w = threadIdx.x >> 6;
    if (lane == 0) wsum[w] = s;
    __syncthreads();
    if (threadIdx.x == 0) partials[blockIdx.x] = wsum[0] + wsum[1] + wsum[2] + wsum[3];
}

__global__ void scanpartials_kernel(int* __restrict__ partials, int* __restrict__ ptr) {
    int t = threadIdx.x;
    int v = (t < SCAN_NBLK) ? partials[t] : 0;
    #pragma unroll
    for (int off = 1; off < 64; off <<= 1) {
        int u = __shfl_up(v, off);
        if (t >= off) v += u;
    }
    if (t < SCAN_NBLK) partials[t] = v;
    if (t == 0) ptr[N_NODES] = N_EDGES;
}

__global__ __launch_bounds__(256) void downsweep_kernel(const int* __restrict__ counts,
                                                        const int* __restrict__ partials,
                                                        int* __restrict__ ptr,
                                                        int* __restrict__ cursor) {
    int b = blockIdx.x;
    int t = threadIdx.x;
    int idx = b * 1024 + t * 4;
    int v[4] = {0, 0, 0, 0};
    if (idx + 3 < N_NODES) {
        int4 q = *(const int4*)(counts + idx);
        v[0] = q.x; v[1] = q.y; v[2] = q.z; v[3] = q.w;
    } else {
        #pragma unroll
        for (int i = 0; i < 4; ++i) if (idx + i < N_NODES) v[i] = counts[idx + i];
    }
    int s = v[0] + v[1] + v[2] + v[3];
    int lane = t & 63, w = t >> 6;
    int inc = s;
    #pragma unroll
    for (int off = 1; off < 64; off <<= 1) {
        int u = __shfl_up(inc, off);
        if (lane >= off) inc += u;
    }
    __shared__ int wsum[4];
    if (lane == 63) wsum[w] = inc;
    __syncthreads();
    int wpre = 0;
    #pragma unroll
    for (int i = 0; i < 4; ++i) if (i < w) wpre += wsum[i];
    int excl = wpre + inc - s;
    int run = ((b == 0) ? 0 : partials[b - 1]) + excl;
    #pragma unroll
    for (int i = 0; i < 4; ++i) {
        if (idx + i < N_NODES) {
            ptr[idx + i] = run;
            cursor[idx + i] = run;
            run += v[i];
        }
    }
}

__global__ void scatter_kernel(const int* __restrict__ ei, int* __restrict__ cursor,
                               int* __restrict__ csr) {
    int e = blockIdx.x * blockDim.x + threadIdx.x;
    if (e < N_EDGES) {
        int src = ei[e];
        int dst = ei[N_EDGES + e];
        int pos = atomicAdd(&cursor[dst], 1);
        csr[pos] = src;
    }
}

// f32 -> bf16 (RNE), bit-exact with __float2bfloat16 for normals
__device__ inline unsigned bf16rne(float f) {
    unsigned u = __float_as_uint(f);
    return (u + 0x7fffu + ((u >> 16) & 1u)) >> 16;
}

// ---- GEMM: H[n][c] = sum_k X[n][k] * W[k][c]  (K=128, C=128), reg-blocked ----
// 64 rows x 128 cols per block; 256 threads; each thread 8 rows x 4 cols.
// Writes f32 H (for alpha) and bf16 H (gather table for aggregate).
#define GB_ROWS 64
__global__ __launch_bounds__(256) void gemm_kernel(const float* __restrict__ X,
                                                   const float* __restrict__ W,
                                                   float* __restrict__ Hout,
                                                   unsigned short* __restrict__ Hb,
                                                   int nrows) {
    __shared__ float xt[GB_ROWS][132];
    const int tid = threadIdx.x;
    const int r0 = blockIdx.x * GB_ROWS;
    // stage 64x128 f32 tile (coalesced float4)
    #pragma unroll
    for (int i = 0; i < 8; ++i) {
        int idx = tid + 256 * i;          // 0..2047 float4 slots
        int r = idx >> 5, c4 = (idx & 31) * 4;
        int gr = r0 + r;
        float4 v = make_float4(0.f, 0.f, 0.f, 0.f);
        if (gr < nrows) v = *(const float4*)(X + (size_t)gr * 128 + c4);
        *(float4*)(&xt[r][c4]) = v;
    }
    __syncthreads();
    const int c0 = (tid & 31) * 4;        // 4 cols
    const int rbase = (tid >> 5) * 8;     // 8 rows
    float acc[8][4];
    #pragma unroll
    for (int i = 0; i < 8; ++i)
        #pragma unroll
        for (int j = 0; j < 4; ++j) acc[i][j] = 0.f;
    #pragma unroll 4
    for (int k = 0; k < 128; ++k) {
        float4 w4 = *(const float4*)(W + k * 128 + c0);
        float xv[8];
        #pragma unroll
        for (int i = 0; i < 8; ++i) xv[i] = xt[rbase + i][k];
        #pragma unroll
        for (int i = 0; i < 8; ++i) {
            acc[i][0] = fmaf(xv[i], w4.x, acc[i][0]);
            acc[i][1] = fmaf(xv[i], w4.y, acc[i][1]);
            acc[i][2] = fmaf(xv[i], w4.z, acc[i][2]);
            acc[i][3] = fmaf(xv[i], w4.w, acc[i][3]);
        }
    }
    #pragma unroll
    for (int i = 0; i < 8; ++i) {
        int gr = r0 + rbase + i;
        if (gr < nrows) {
            *(float4*)(Hout + (size_t)gr * 128 + c0) =
                make_float4(acc[i][0], acc[i][1], acc[i][2], acc[i][3]);
            uint2 p;
            p.x = bf16rne(acc[i][0]) | (bf16rne(acc[i][1]) << 16);
            p.y = bf16rne(acc[i][2]) | (bf16rne(acc[i][3]) << 16);
            *(uint2*)(Hb + (size_t)gr * 128 + c0) = p;
        }
    }
}

// ---------------- per-node attention logits ----------------
template <int H>
__global__ __launch_bounds__(256) void alpha_kernel(const float* __restrict__ Hm,
                                                    const float* __restrict__ a_src,
                                                    const float* __restrict__ a_dst,
                                                    float* __restrict__ als,
                                                    float* __restrict__ ald) {
    int wid = ((blockIdx.x * blockDim.x + threadIdx.x) >> 6);
    int lane = threadIdx.x & 63;
    if (wid >= N_NODES) return;
    float v0 = Hm[(size_t)wid * 128 + lane];
    float v1 = Hm[(size_t)wid * 128 + 64 + lane];
    if (H == 2) {
        float s0 = v0 * a_src[lane];
        float s1 = v1 * a_src[64 + lane];
        float d0 = v0 * a_dst[lane];
        float d1 = v1 * a_dst[64 + lane];
        #pragma unroll
        for (int off = 32; off; off >>= 1) {
            s0 += __shfl_down(s0, off);
            s1 += __shfl_down(s1, off);
            d0 += __shfl_down(d0, off);
            d1 += __shfl_down(d1, off);
        }
        if (lane == 0) {
            als[wid * 2] = s0; als[wid * 2 + 1] = s1;
            ald[wid * 2] = d0; ald[wid * 2 + 1] = d1;
        }
    } else {
        float s = v0 * a_src[lane] + v1 * a_src[64 + lane];
        float d = v0 * a_dst[lane] + v1 * a_dst[64 + lane];
        #pragma unroll
        for (int off = 32; off; off >>= 1) {
            s += __shfl_down(s, off);
            d += __shfl_down(d, off);
        }
        if (lane == 0) { als[wid] = s; ald[wid] = d; }
    }
}

// ---- fused edge-softmax + aggregation (one wave per dst; bf16 gathers) ----
template <int H, int DO_ELU>
__global__ __launch_bounds__(256) void aggregate_kernel(const unsigned short* __restrict__ Hb,
                                                        const float* __restrict__ als,
                                                        const float* __restrict__ aldv,
                                                        const int* __restrict__ ptr,
                                                        const int* __restrict__ csr,
                                                        const float* __restrict__ bias,
                                                        float* __restrict__ out) {
    int wid = blockIdx.x * (blockDim.x >> 6) + (threadIdx.x >> 6);
    int lane = threadIdx.x & 63;
    if (wid >= N_NODES) return;
    const int d = wid;
    const int head = (H == 2) ? (lane >> 5) : 0;
    const float ald = aldv[d * H + head];

    float m0, m1, m2, m3, l0, l1, l2, l3;
    float a0x, a0y, a1x, a1y, a2x, a2y, a3x, a3y;
    { // state 0 init = self-loop
        float e = als[d * H + head] + ald;
        e = e > 0.f ? e : NEG_SLOPE * e;
        m0 = e; l0 = 1.f;
        unsigned u = ((const unsigned*)(Hb + (size_t)d * 128))[lane];
        a0x = __uint_as_float(u << 16);
        a0y = __uint_as_float(u & 0xffff0000u);
    }
    m1 = m2 = m3 = -INFINITY;
    l1 = l2 = l3 = 0.f;
    a1x = a1y = a2x = a2y = a3x = a3y = 0.f;

#define UPDATE(S, SRC) do {                                                   \
        int _s = (SRC);                                                       \
        float _e = als[_s * H + head] + ald;                                  \
        _e = _e > 0.f ? _e : NEG_SLOPE * _e;                                  \
        unsigned _u = ((const unsigned*)(Hb + (size_t)_s * 128))[lane];       \
        float _hx = __uint_as_float(_u << 16);                                \
        float _hy = __uint_as_float(_u & 0xffff0000u);                        \
        float _mn = fmaxf(m##S, _e);                                          \
        float _sc = __expf(m##S - _mn);                                       \
        float _p  = __expf(_e - _mn);                                         \
        l##S  = fmaf(l##S, _sc, _p);                                          \
        a##S##x = fmaf(a##S##x, _sc, _p * _hx);                               \
        a##S##y = fmaf(a##S##y, _sc, _p * _hy);                               \
        m##S = _mn;                                                           \
    } while (0)

    int beg = ptr[d], end = ptr[d + 1];
    int k = beg;
    for (; k + 3 < end; k += 4) {
        int s0 = csr[k], s1 = csr[k + 1], s2 = csr[k + 2], s3 = csr[k + 3];
        UPDATE(0, s0);
        UPDATE(1, s1);
        UPDATE(2, s2);
        UPDATE(3, s3);
    }
    if (k < end) { UPDATE(0, csr[k]); ++k; }
    if (k < end) { UPDATE(1, csr[k]); ++k; }
    if (k < end) { UPDATE(2, csr[k]); ++k; }
#undef UPDATE

    float M = fmaxf(fmaxf(m0, m1), fmaxf(m2, m3));
    float w0 = __expf(m0 - M), w1 = __expf(m1 - M);
    float w2 = __expf(m2 - M), w3 = __expf(m3 - M);
    float L  = l0 * w0 + l1 * w1 + l2 * w2 + l3 * w3;
    float ax = a0x * w0 + a1x * w1 + a2x * w2 + a3x * w3;
    float ay = a0y * w0 + a1y * w1 + a2y * w2 + a3y * w3;

    float inv = 1.f / (L + 1e-16f);
    float o0 = ax * inv + bias[2 * lane];
    float o1 = ay * inv + bias[2 * lane + 1];
    if (DO_ELU) {
        o0 = o0 > 0.f ? o0 : expm1f(o0);
        o1 = o1 > 0.f ? o1 : expm1f(o1);
    }
    ((float2*)(out + (size_t)d * 128))[lane] = make_float2(o0, o1);
}

// ---------------- launch ----------------
extern "C" void kernel_launch(void* const* d_in, const int* in_sizes, int n_in,
                              void* d_out, int out_size, void* d_ws, size_t ws_size,
                              hipStream_t stream) {
    const float* x      = (const float*)d_in[0];
    const int*   ei     = (const int*)d_in[1];
    const float* W1     = (const float*)d_in[2];
    const float* a_src1 = (const float*)d_in[3];
    const float* a_dst1 = (const float*)d_in[4];
    const float* b1     = (const float*)d_in[5];
    const float* W2     = (const float*)d_in[6];
    const float* a_src2 = (const float*)d_in[7];
    const float* a_dst2 = (const float*)d_in[8];
    const float* b2     = (const float*)d_in[9];
    float* out = (float*)d_out;

    char* ws = (char*)d_ws;
    size_t off = 0;
    auto alloc = [&](size_t bytes) { void* p = ws + off; off += (bytes + 255) & ~(size_t)255; return p; };
    int*   ptr      = (int*)alloc((N_NODES + 1) * sizeof(int));
    int*   cursor   = (int*)alloc(N_NODES * sizeof(int));
    int*   counts   = (int*)alloc(N_NODES * sizeof(int));
    int*   partials = (int*)alloc(SCAN_NBLK * sizeof(int));
    int*   csr      = (int*)alloc(N_EDGES * sizeof(int));
    float* h        = (float*)alloc((size_t)N_NODES * 128 * sizeof(float));
    float* x2       = (float*)alloc((size_t)N_NODES * 128 * sizeof(float));
    unsigned short* hb = (unsigned short*)alloc((size_t)N_NODES * 128 * sizeof(unsigned short));
    float* als      = (float*)alloc(N_NODES * 2 * sizeof(float));
    float* ald      = (float*)alloc(N_NODES * 2 * sizeof(float));

    // ---- CSR build (same graph both layers) ----
    hipMemsetAsync(counts, 0, N_NODES * sizeof(int), stream);
    int eblocks = (N_EDGES + 255) / 256;
    count_kernel<<<eblocks, 256, 0, stream>>>(ei, counts);
    blocksum_kernel<<<SCAN_NBLK, 256, 0, stream>>>(counts, partials);
    scanpartials_kernel<<<1, 64, 0, stream>>>(partials, ptr);
    downsweep_kernel<<<SCAN_NBLK, 256, 0, stream>>>(counts, partials, ptr, cursor);
    scatter_kernel<<<eblocks, 256, 0, stream>>>(ei, cursor, csr);

    int gblocks = (N_NODES + GB_ROWS - 1) / GB_ROWS;
    int wblocks = (N_NODES + 3) / 4;

    // ---- layer 1 ----
    gemm_kernel<<<gblocks, 256, 0, stream>>>(x, W1, h, hb, N_NODES);
    alpha_kernel<2><<<wblocks, 256, 0, stream>>>(h, a_src1, a_dst1, als, ald);
    aggregate_kernel<2, 1><<<wblocks, 256, 0, stream>>>(hb, als, ald, ptr, csr, b1, x2);

    // ---- layer 2 ----
    gemm_kernel<<<gblocks, 256, 0, stream>>>(x2, W2, h, hb, N_NODES);
    alpha_kernel<1><<<wblocks, 256, 0, stream>>>(h, a_src2, a_dst2, als, ald);
    aggregate_kernel<1, 0><<<wblocks, 256, 0, stream>>>(hb, als, ald, ptr, csr, b2, out);
}